// Round 3
// baseline (438.476 us; speedup 1.0000x reference)
//
#include <hip/hip_runtime.h>
#include <math.h>

// MS-SSIM loss, 5 levels, 11-tap separable Gaussian (sigma=1.5), VALID padding.
// Round 3: no input staging (direct coalesced global reads in h-pass),
// hb stride 36 (bank-conflict-free ds_write_b128), 1 barrier per block.

#define TILE 32
#define TIN  42          // TILE + 10 (halo for 11-tap valid conv)
#define HBS  36          // hb row stride in floats (conflict-free: 36%32=4)

struct GWin { float w[11]; };

__global__ __launch_bounds__(256)
void ssim_level_kernel(const float* __restrict__ X, const float* __restrict__ Y,
                       float* __restrict__ poolX, float* __restrict__ poolY,
                       float* __restrict__ accum,   // [0..95]=ssim sums, [96..191]=cs sums
                       int S, int outS, int doPool, GWin gw)
{
    __shared__ float hb[5 * TIN * HBS];   // hb[m][r][c] = hb[m*TIN*HBS + r*HBS + c]
    __shared__ float rs[4], rc[4];

    const int ch  = blockIdx.z;      // 0..95 (n*c)
    const int gx0 = blockIdx.x * TILE;
    const int gy0 = blockIdx.y * TILE;
    const int tid = threadIdx.x;

    const float* Xc = X + (size_t)ch * S * S;
    const float* Yc = Y + (size_t)ch * S * S;

    // ---- 2x2 avg-pool into next level (independent; loads overlap h-pass) ----
    if (doPool) {
        int pr = tid >> 4, pc = tid & 15;      // 16x16 pooled outputs per block
        int halfS = S >> 1;
        int py = (gy0 >> 1) + pr, px = (gx0 >> 1) + pc;
        int r = gy0 + 2 * pr, c = gx0 + 2 * pc;
        float2 x0 = *reinterpret_cast<const float2*>(Xc + (size_t)r * S + c);
        float2 x1 = *reinterpret_cast<const float2*>(Xc + (size_t)(r + 1) * S + c);
        float2 y0 = *reinterpret_cast<const float2*>(Yc + (size_t)r * S + c);
        float2 y1 = *reinterpret_cast<const float2*>(Yc + (size_t)(r + 1) * S + c);
        float xa = 0.25f * (x0.x + x0.y + x1.x + x1.y);
        float ya = 0.25f * (y0.x + y0.y + y1.x + y1.y);
        size_t o = (size_t)ch * halfS * halfS + (size_t)py * halfS + px;
        poolX[o] = xa;
        poolY[o] = ya;
    }

    // ---- horizontal 11-tap pass, 4-wide output groups, direct global reads ----
    // 42 rows * 8 groups = 336 groups of 4 outputs
    const bool interior = (gx0 + 44 <= S);   // block-uniform
    for (int g = tid; g < TIN * 8; g += 256) {
        int r  = g >> 3;
        int c4 = (g & 7) * 4;
        int gr = gy0 + r; if (gr > S - 1) gr = S - 1;   // clamped rows feed only invalid outputs
        const float* xrow = Xc + (size_t)gr * S;
        const float* yrow = Yc + (size_t)gr * S;
        float xv[16], yv[16];
        if (interior) {
            int gc = gx0 + c4;
            *reinterpret_cast<float4*>(&xv[0])  = *reinterpret_cast<const float4*>(xrow + gc);
            *reinterpret_cast<float4*>(&xv[4])  = *reinterpret_cast<const float4*>(xrow + gc + 4);
            *reinterpret_cast<float4*>(&xv[8])  = *reinterpret_cast<const float4*>(xrow + gc + 8);
            *reinterpret_cast<float4*>(&xv[12]) = *reinterpret_cast<const float4*>(xrow + gc + 12);
            *reinterpret_cast<float4*>(&yv[0])  = *reinterpret_cast<const float4*>(yrow + gc);
            *reinterpret_cast<float4*>(&yv[4])  = *reinterpret_cast<const float4*>(yrow + gc + 4);
            *reinterpret_cast<float4*>(&yv[8])  = *reinterpret_cast<const float4*>(yrow + gc + 8);
            *reinterpret_cast<float4*>(&yv[12]) = *reinterpret_cast<const float4*>(yrow + gc + 12);
        } else {
            #pragma unroll
            for (int i = 0; i < 14; ++i) {
                int gc = gx0 + c4 + i; if (gc > S - 1) gc = S - 1;  // clamped cols feed only invalid outputs
                xv[i] = xrow[gc];
                yv[i] = yrow[gc];
            }
            xv[14] = xv[15] = yv[14] = yv[15] = 0.f;
        }
        float xx[14], yy[14], xy[14];
        #pragma unroll
        for (int i = 0; i < 14; ++i) {
            xx[i] = xv[i] * xv[i];
            yy[i] = yv[i] * yv[i];
            xy[i] = xv[i] * yv[i];
        }
        float a[5][4];
        #pragma unroll
        for (int m = 0; m < 5; ++m)
            #pragma unroll
            for (int j = 0; j < 4; ++j) a[m][j] = 0.f;
        #pragma unroll
        for (int j = 0; j < 4; ++j) {
            #pragma unroll
            for (int k = 0; k < 11; ++k) {
                float w = gw.w[k];
                a[0][j] += w * xv[j + k];
                a[1][j] += w * yv[j + k];
                a[2][j] += w * xx[j + k];
                a[3][j] += w * yy[j + k];
                a[4][j] += w * xy[j + k];
            }
        }
        #pragma unroll
        for (int m = 0; m < 5; ++m) {
            *reinterpret_cast<float4*>(&hb[m * (TIN * HBS) + r * HBS + c4]) =
                make_float4(a[m][0], a[m][1], a[m][2], a[m][3]);
        }
    }
    __syncthreads();

    // ---- vertical 11-tap pass: 1x4 vertical output group per thread ----
    const float C1 = 1e-4f, C2 = 9e-4f;
    float ssum = 0.f, csum = 0.f;
    {
        int c  = tid & 31;
        int r0 = (tid >> 5) * 4;            // 8 strips * 4 rows = 32
        float acc[5][4];
        #pragma unroll
        for (int m = 0; m < 5; ++m)
            #pragma unroll
            for (int j = 0; j < 4; ++j) acc[m][j] = 0.f;
        const float* hbp = &hb[r0 * HBS + c];
        #pragma unroll
        for (int m = 0; m < 5; ++m) {
            #pragma unroll
            for (int k = 0; k < 14; ++k) {
                float v = hbp[m * (TIN * HBS) + k * HBS];
                #pragma unroll
                for (int j = 0; j < 4; ++j) {
                    if (j <= k && k - j <= 10)
                        acc[m][j] += gw.w[k - j] * v;
                }
            }
        }
        int ox = gx0 + c;
        #pragma unroll
        for (int j = 0; j < 4; ++j) {
            int oy = gy0 + r0 + j;
            if (oy < outS && ox < outS) {
                float m1  = acc[0][j], m2 = acc[1][j];
                float e11 = acc[2][j], e22 = acc[3][j], e12 = acc[4][j];
                float mu12 = m1 * m2;
                float m1sq = m1 * m1, m2sq = m2 * m2;
                float s11  = e11 - m1sq;
                float s22  = e22 - m2sq;
                float s12  = e12 - mu12;
                float cs = (2.f * s12 + C2) * __builtin_amdgcn_rcpf(s11 + s22 + C2);
                float ss = (2.f * mu12 + C1) * __builtin_amdgcn_rcpf(m1sq + m2sq + C1) * cs;
                ssum += ss;
                csum += cs;
            }
        }
    }

    // ---- block reduction + atomic accumulate ----
    for (int off = 32; off > 0; off >>= 1) {
        ssum += __shfl_down(ssum, off);
        csum += __shfl_down(csum, off);
    }
    int wid = tid >> 6, lane = tid & 63;
    if (lane == 0) { rs[wid] = ssum; rc[wid] = csum; }
    __syncthreads();
    if (tid == 0) {
        float s = rs[0] + rs[1] + rs[2] + rs[3];
        float c = rc[0] + rc[1] + rc[2] + rc[3];
        atomicAdd(&accum[ch], s);
        atomicAdd(&accum[96 + ch], c);
    }
}

__global__ void finalize_kernel(const float* __restrict__ accum, float* __restrict__ out)
{
    __shared__ float red[2];
    const int t = threadIdx.x;   // 128 threads
    const float w[5]   = {0.0448f, 0.2856f, 0.3001f, 0.2363f, 0.1333f};
    const float inv[5] = {1.f / (502.f * 502.f), 1.f / (246.f * 246.f),
                          1.f / (118.f * 118.f), 1.f / (54.f * 54.f),
                          1.f / (22.f * 22.f)};
    float ms = 0.f;
    if (t < 96) {
        ms = 1.f;
        #pragma unroll
        for (int l = 0; l < 5; ++l) {
            float v = (l < 4) ? accum[l * 192 + 96 + t] : accum[l * 192 + t];
            v *= inv[l];
            v = fmaxf(v, 0.f);
            ms *= powf(v, w[l]);
        }
    }
    for (int off = 32; off > 0; off >>= 1) ms += __shfl_down(ms, off);
    int wid = t >> 6, lane = t & 63;
    if (lane == 0) red[wid] = ms;
    __syncthreads();
    if (t == 0) out[0] = 1.f - (red[0] + red[1]) * (1.f / 96.f);
}

extern "C" void kernel_launch(void* const* d_in, const int* in_sizes, int n_in,
                              void* d_out, int out_size, void* d_ws, size_t ws_size,
                              hipStream_t stream)
{
    (void)in_sizes; (void)n_in; (void)out_size; (void)ws_size;
    const float* X = (const float*)d_in[0];
    const float* Y = (const float*)d_in[1];
    float* out = (float*)d_out;
    float* ws  = (float*)d_ws;

    // Gaussian window (size 11, sigma 1.5), normalized
    GWin gw;
    {
        double g[11], s = 0.0;
        for (int i = 0; i < 11; ++i) { double d = i - 5; g[i] = exp(-(d * d) / 4.5); s += g[i]; }
        for (int i = 0; i < 11; ++i) gw.w[i] = (float)(g[i] / s);
    }

    // workspace layout (floats)
    float* accum = ws;                 // 5 levels * 192
    size_t off = 1024;
    float* p1x = ws + off; off += (size_t)96 * 256 * 256;
    float* p1y = ws + off; off += (size_t)96 * 256 * 256;
    float* p2x = ws + off; off += (size_t)96 * 128 * 128;
    float* p2y = ws + off; off += (size_t)96 * 128 * 128;
    float* p3x = ws + off; off += (size_t)96 * 64 * 64;
    float* p3y = ws + off; off += (size_t)96 * 64 * 64;
    float* p4x = ws + off; off += (size_t)96 * 32 * 32;
    float* p4y = ws + off; off += (size_t)96 * 32 * 32;

    hipMemsetAsync(accum, 0, 5 * 192 * sizeof(float), stream);

    // level grids: tiles*32 == S at every level, so fused pooling exactly
    // covers the next level.
    ssim_level_kernel<<<dim3(16, 16, 96), 256, 0, stream>>>(X,   Y,   p1x, p1y, accum + 0,   512, 502, 1, gw);
    ssim_level_kernel<<<dim3(8,  8,  96), 256, 0, stream>>>(p1x, p1y, p2x, p2y, accum + 192, 256, 246, 1, gw);
    ssim_level_kernel<<<dim3(4,  4,  96), 256, 0, stream>>>(p2x, p2y, p3x, p3y, accum + 384, 128, 118, 1, gw);
    ssim_level_kernel<<<dim3(2,  2,  96), 256, 0, stream>>>(p3x, p3y, p4x, p4y, accum + 576, 64,  54,  1, gw);
    ssim_level_kernel<<<dim3(1,  1,  96), 256, 0, stream>>>(p4x, p4y, nullptr, nullptr, accum + 768, 32, 22, 0, gw);

    finalize_kernel<<<1, 128, 0, stream>>>(accum, out);
}